// Round 9
// baseline (420.610 us; speedup 1.0000x reference)
//
#include <hip/hip_runtime.h>
#include <hip/hip_fp16.h>

#define NEG_SLOPE 0.2f

constexpr int NN = 50000;   // nodes
constexpr int EE = 800000;  // edges (before self loops)

static inline int cdiv(int a, int b) { return (a + b - 1) / b; }

typedef _Float16 h2 __attribute__((ext_vector_type(2)));

#if __has_builtin(__builtin_amdgcn_fdot2)
static __device__ inline float fdot2f(h2 a, h2 b, float c) {
    return __builtin_amdgcn_fdot2(a, b, c, false);
}
#else
static __device__ inline float fdot2f(h2 a, h2 b, float c) {
    return c + (float)a.x * (float)b.x + (float)a.y * (float)b.y;
}
#endif

static __device__ inline h2 bch2(unsigned u) { return __builtin_bit_cast(h2, u); }

// 32-byte edge record: fp16 edge attrs + src id (always within one 64B line)
struct __align__(16) ERec {
    __half ea[8];   // 16 B
    int src;        // 4 B
    int pad[3];     // 12 B
};

// ================= CSR build =================
__global__ void hist_kernel(const int4* __restrict__ dst4, int* __restrict__ rowcnt, int E4) {
    int t = blockIdx.x * blockDim.x + threadIdx.x;
    if (t >= E4) return;
    int4 d = dst4[t];
    atomicAdd(&rowcnt[d.x], 1);
    atomicAdd(&rowcnt[d.y], 1);
    atomicAdd(&rowcnt[d.z], 1);
    atomicAdd(&rowcnt[d.w], 1);
}

__global__ void scana_kernel(const int* __restrict__ cnt, int* __restrict__ blocksum, int n) {
    __shared__ int s[256];
    int t = threadIdx.x, g = blockIdx.x * 256 + t;
    s[t] = (g < n) ? cnt[g] + 1 : 0;
    __syncthreads();
    for (int off = 128; off > 0; off >>= 1) {
        if (t < off) s[t] += s[t + off];
        __syncthreads();
    }
    if (t == 0) blocksum[blockIdx.x] = s[0];
}

__global__ void scanb_kernel(const int* __restrict__ cnt, const int* __restrict__ blocksum,
                             int nbk, int* __restrict__ rowptr, int* __restrict__ cursor,
                             ERec* __restrict__ csr, int n) {
    __shared__ int bs[256];
    __shared__ int s[256];
    int t = threadIdx.x;
    bs[t] = (t < nbk) ? blocksum[t] : 0;
    __syncthreads();
    for (int off = 1; off < 256; off <<= 1) {
        int tv = (t >= off) ? bs[t - off] : 0; __syncthreads();
        bs[t] += tv; __syncthreads();
    }
    int blockoff = (blockIdx.x > 0) ? bs[blockIdx.x - 1] : 0;
    int g = blockIdx.x * 256 + t;
    int val = (g < n) ? cnt[g] + 1 : 0;
    s[t] = val; __syncthreads();
    for (int off = 1; off < 256; off <<= 1) {
        int tv = (t >= off) ? s[t - off] : 0; __syncthreads();
        s[t] += tv; __syncthreads();
    }
    if (g >= n) return;
    int incl = s[t] + blockoff;
    rowptr[g + 1] = incl;
    int beg = incl - val;
    cursor[g] = beg + 1;          // slot `beg` reserved for the self loop
    csr[beg].src = g;             // self-loop source
    if (g == 0) rowptr[0] = 0;
}

__global__ void scatter_kernel(const int* __restrict__ src, const int* __restrict__ dst,
                               const float* __restrict__ eattr,
                               int* __restrict__ cursor, ERec* __restrict__ csr, int E) {
    int t = blockIdx.x * blockDim.x + threadIdx.x;
    if (t >= E) return;
    int d = dst[t];
    int pos = atomicAdd(&cursor[d], 1);
    const float4* ea4 = (const float4*)(eattr + (size_t)t * 8);
    float4 a = ea4[0], b = ea4[1];
    __half2 h0 = __floats2half2_rn(a.x, a.y);
    __half2 h1 = __floats2half2_rn(a.z, a.w);
    __half2 h2v = __floats2half2_rn(b.x, b.y);
    __half2 h3 = __floats2half2_rn(b.z, b.w);
    uint4 u;
    u.x = *(unsigned*)&h0; u.y = *(unsigned*)&h1;
    u.z = *(unsigned*)&h2v; u.w = *(unsigned*)&h3;
    ERec* r = &csr[pos];
    *(uint4*)r->ea = u;
    r->src = src[t];
}

// ======= fused: node_linear layer-1 (blocks < NB1) + loop_sea (rest) =========
template <int NB1>
__global__ __launch_bounds__(256) void fused_nl1_loopsea_kernel(
    const float* __restrict__ x,
    const float* __restrict__ Wl, const float* __restrict__ bl,
    const float* __restrict__ Wr, const float* __restrict__ br,
    __half* __restrict__ xl, __half* __restrict__ xr,
    const int* __restrict__ rowptr, ERec* __restrict__ csr, int n) {
    constexpr int K = 16, CT = 32, NPB = 8;
    __shared__ float Wls[K * CT];
    __shared__ float Wrs[K * CT];
    __shared__ float xs[NPB * K];
    int tid = threadIdx.x;
    if (blockIdx.x < NB1) {
        int ty = tid >> 5, c = tid & 31;
        for (int i = tid; i < K * CT; i += 256) { Wls[i] = Wl[i]; Wrs[i] = Wr[i]; }
        int node0 = blockIdx.x * NPB;
        for (int i = tid; i < NPB * K; i += 256) {
            int nd = node0 + i / K;
            xs[i] = (nd < n) ? x[(size_t)node0 * K + i] : 0.f;
        }
        __syncthreads();
        int node = node0 + ty;
        if (node >= n) return;
        float aL = bl[c], aR = br[c];
        const float* xrow = &xs[ty * K];
        for (int k = 0; k < K; ++k) {
            float xv = xrow[k];
            aL = fmaf(xv, Wls[k * CT + c], aL);
            aR = fmaf(xv, Wrs[k * CT + c], aR);
        }
        xl[(size_t)node * CT + c] = __float2half(aL);
        xr[(size_t)node * CT + c] = __float2half(aR);
    } else {
        int wave = ((blockIdx.x - NB1) * 256 + tid) >> 6;
        int lane = tid & 63;
        if (wave >= n) return;
        int beg = rowptr[wave], end = rowptr[wave + 1];
        int k = lane & 7, j0 = lane >> 3;
        float s = 0.f;
        for (int j = beg + 1 + j0; j < end; j += 8)
            s += __half2float(csr[j].ea[k]);
        s += __shfl_xor(s, 8); s += __shfl_xor(s, 16); s += __shfl_xor(s, 32);
        int cnt = end - beg - 1;
        if (lane < 8) csr[beg].ea[lane] = __float2half(s / fmaxf((float)cnt, 1.f));
    }
}

// ======= node linear (fp16 input, fp16 LDS weights, fdot2, node-loop) ========
template <int K, int CT, int NPB>
__global__ __launch_bounds__(256) void node_linear_h_kernel(
    const __half* __restrict__ x,
    const float* __restrict__ Wl, const float* __restrict__ bl,
    const float* __restrict__ Wr, const float* __restrict__ br,
    __half* __restrict__ xl, __half* __restrict__ xr, int n) {
    constexpr int K2 = K / 2;
    constexpr int TS = 256 / CT;     // node-slots per pass
    __shared__ h2 Wls[K2 * CT];
    __shared__ h2 Wrs[K2 * CT];
    __shared__ h2 xs[NPB * K2];
    int tid = threadIdx.x;
    for (int i = tid; i < K2 * CT; i += 256) {
        int k2 = i / CT, c = i % CT;
        Wls[i] = h2{(_Float16)Wl[(2 * k2) * CT + c], (_Float16)Wl[(2 * k2 + 1) * CT + c]};
        Wrs[i] = h2{(_Float16)Wr[(2 * k2) * CT + c], (_Float16)Wr[(2 * k2 + 1) * CT + c]};
    }
    int node0 = blockIdx.x * NPB;
    const unsigned* xg = (const unsigned*)(x + (size_t)node0 * K);
    for (int i = tid; i < NPB * K2; i += 256) {
        int nd = node0 + i / K2;
        unsigned u = (nd < n) ? xg[i] : 0u;
        xs[i] = bch2(u);
    }
    __syncthreads();
    int c = tid % CT, ty = tid / CT;
    int bound = (node0 + NPB < n) ? NPB : (n - node0);
    for (int local = ty; local < bound; local += TS) {
        int node = node0 + local;
        float aL = bl[c], aR = br[c];
        const h2* xrow = &xs[local * K2];
        for (int k = 0; k < K2; ++k) {
            h2 xv = xrow[k];
            aL = fdot2f(xv, Wls[k * CT + c], aL);
            aR = fdot2f(xv, Wrs[k * CT + c], aR);
        }
        xl[(size_t)node * CT + c] = __float2half(aL);
        xr[(size_t)node * CT + c] = __float2half(aR);
    }
}

// ======= layer-2 node linear + residual: xl, xr, and res = b2 + hA @ Rw =======
template <int NPB>
__global__ __launch_bounds__(256) void nlh2_res_kernel(
    const __half* __restrict__ x,   // hA [N,32]
    const float* __restrict__ Wl, const float* __restrict__ bl,
    const float* __restrict__ Wr, const float* __restrict__ br,
    const float* __restrict__ Rw,   // [32,128] fp32
    const float* __restrict__ b2,   // [128]
    __half* __restrict__ xl, __half* __restrict__ xr,
    __half* __restrict__ res, int n) {
    constexpr int K = 32, CT = 128, K2 = K / 2;
    __shared__ h2 Wls[K2 * CT];
    __shared__ h2 Wrs[K2 * CT];
    __shared__ float Rws[K * CT];
    __shared__ h2 xs[NPB * K2];
    int tid = threadIdx.x;
    for (int i = tid; i < K2 * CT; i += 256) {
        int k2 = i / CT, c = i % CT;
        Wls[i] = h2{(_Float16)Wl[(2 * k2) * CT + c], (_Float16)Wl[(2 * k2 + 1) * CT + c]};
        Wrs[i] = h2{(_Float16)Wr[(2 * k2) * CT + c], (_Float16)Wr[(2 * k2 + 1) * CT + c]};
    }
    for (int i = tid; i < K * CT; i += 256) Rws[i] = Rw[i];
    int node0 = blockIdx.x * NPB;
    const unsigned* xg = (const unsigned*)(x + (size_t)node0 * K);
    for (int i = tid; i < NPB * K2; i += 256) {
        int nd = node0 + i / K2;
        unsigned u = (nd < n) ? xg[i] : 0u;
        xs[i] = bch2(u);
    }
    __syncthreads();
    int c = tid & 127, ty = tid >> 7;   // 2 node-slots
    int bound = (node0 + NPB < n) ? NPB : (n - node0);
    for (int local = ty; local < bound; local += 2) {
        int node = node0 + local;
        float aL = bl[c], aR = br[c], aS = b2[c];
        const h2* xrow = &xs[local * K2];
        for (int k = 0; k < K2; ++k) {
            h2 xv = xrow[k];
            aL = fdot2f(xv, Wls[k * CT + c], aL);
            aR = fdot2f(xv, Wrs[k * CT + c], aR);
            aS = fmaf((float)xv.x, Rws[(2 * k) * CT + c], aS);
            aS = fmaf((float)xv.y, Rws[(2 * k + 1) * CT + c], aS);
        }
        xl[(size_t)node * CT + c] = __float2half(aL);
        xr[(size_t)node * CT + c] = __float2half(aR);
        res[(size_t)node * CT + c] = __float2half(aS);
    }
}

// ================= CSR aggregation, CT=128 (layer 2) =================
// One wave per node; 4 edge-chains per wave (16 lanes each, 8 ch/lane):
// 4 edges per wave-iteration -> loop control / VMEM issues / pipeline shifts
// amortized 2x vs the 2-chain version; head reduce = 2 shfls (4-lane head).
// Decoupled pipeline kept: records 3 steps ahead, xl gather uses a src id
// loaded 2 iterations earlier. RES: residual pre-written into `out`.
template <bool RELU, bool RES>
__global__ __launch_bounds__(256) void agg128_kernel(
    const int* __restrict__ rowptr, const ERec* __restrict__ csr,
    const __half* __restrict__ xl, const __half* __restrict__ xr,
    const float* __restrict__ We,   // [8,128]
    const float* __restrict__ att,  // flat [128]
    const float* __restrict__ bias, // [128] (used only when !RES)
    __half* __restrict__ out, int n) {
    int tid = threadIdx.x;
    int node = (blockIdx.x * 256 + tid) >> 6;
    int lane = tid & 63;
    if (node >= n) return;
    int sub = lane >> 4, cl = lane & 15;
    int c0 = 8 * cl;
    h2 wch[8][4];
    float attc[8];
#pragma unroll
    for (int c = 0; c < 8; ++c) {
        attc[c] = att[c0 + c];
#pragma unroll
        for (int k = 0; k < 4; ++k)
            wch[c][k] = h2{(_Float16)We[(2 * k) * 128 + c0 + c],
                           (_Float16)We[(2 * k + 1) * 128 + c0 + c]};
    }
    int beg = rowptr[node], end = rowptr[node + 1];
    uint4 xru = *(const uint4*)&xr[(size_t)node * 128 + c0];
    h2 xr01 = bch2(xru.x), xr23 = bch2(xru.y), xr45 = bch2(xru.z), xr67 = bch2(xru.w);
    float xrc[8] = {(float)xr01.x, (float)xr01.y, (float)xr23.x, (float)xr23.y,
                    (float)xr45.x, (float)xr45.y, (float)xr67.x, (float)xr67.y};
    float num[8] = {0.f, 0.f, 0.f, 0.f, 0.f, 0.f, 0.f, 0.f};
    float den = 0.f;

    int j = beg + sub;
    // --- pipeline state: records at j, j+4, j+8 in flight; x for edge j ---
    uint4 u0, u1, u2; int s0, s1, s2; uint4 x0;
    if (j < end)     { u0 = *(const uint4*)csr[j].ea;     s0 = csr[j].src; }
    if (j + 4 < end) { u1 = *(const uint4*)csr[j + 4].ea; s1 = csr[j + 4].src; }
    if (j + 8 < end) { u2 = *(const uint4*)csr[j + 8].ea; s2 = csr[j + 8].src; }
    if (j < end)     x0 = *(const uint4*)&xl[(size_t)s0 * 128 + c0];
    while (j < end) {
        uint4 uT; int sT; uint4 xT;
        if (j + 12 < end) { uT = *(const uint4*)csr[j + 12].ea; sT = csr[j + 12].src; }
        if (j + 4 < end)  { xT = *(const uint4*)&xl[(size_t)s1 * 128 + c0]; } // s1: 2 iters old
        h2 e0 = bch2(u0.x), e1 = bch2(u0.y), e2 = bch2(u0.z), e3 = bch2(u0.w);
        h2 xl01 = bch2(x0.x), xl23 = bch2(x0.y), xl45 = bch2(x0.z), xl67 = bch2(x0.w);
        float xls[8] = {(float)xl01.x, (float)xl01.y, (float)xl23.x, (float)xl23.y,
                        (float)xl45.x, (float)xl45.y, (float)xl67.x, (float)xl67.y};
        float p = 0.f;
#pragma unroll
        for (int c = 0; c < 8; ++c) {
            float m = xls[c] + xrc[c];
            m = fdot2f(e0, wch[c][0], m); m = fdot2f(e1, wch[c][1], m);
            m = fdot2f(e2, wch[c][2], m); m = fdot2f(e3, wch[c][3], m);
            float sv = fmaxf(m, 0.f) + NEG_SLOPE * fminf(m, 0.f);
            p = fmaf(sv, attc[c], p);
        }
        p += __shfl_xor(p, 1); p += __shfl_xor(p, 2);   // 4-lane head reduce
        float wgt = __expf(p);
#pragma unroll
        for (int c = 0; c < 8; ++c) num[c] = fmaf(wgt, xls[c], num[c]);
        den += wgt;
        j += 4;
        u0 = u1; u1 = u2; u2 = uT;
        s1 = s2; s2 = sT;
        x0 = xT;
    }
    // combine the four 16-lane chains
#pragma unroll
    for (int c = 0; c < 8; ++c) {
        num[c] += __shfl_xor(num[c], 16);
        num[c] += __shfl_xor(num[c], 32);
    }
    den += __shfl_xor(den, 16);
    den += __shfl_xor(den, 32);
    if (sub == 0) {
        float inv = 1.f / den;
        float base[8];
        if (RES) {
            uint4 ru = *(const uint4*)&out[(size_t)node * 128 + c0];
            h2 r01 = bch2(ru.x), r23 = bch2(ru.y), r45 = bch2(ru.z), r67 = bch2(ru.w);
            base[0] = (float)r01.x; base[1] = (float)r01.y;
            base[2] = (float)r23.x; base[3] = (float)r23.y;
            base[4] = (float)r45.x; base[5] = (float)r45.y;
            base[6] = (float)r67.x; base[7] = (float)r67.y;
        } else {
#pragma unroll
            for (int c = 0; c < 8; ++c) base[c] = bias[c0 + c];
        }
        float v[8];
#pragma unroll
        for (int c = 0; c < 8; ++c) v[c] = fmaf(num[c], inv, base[c]);
        if (RELU) {
#pragma unroll
            for (int c = 0; c < 8; ++c) v[c] = fmaxf(v[c], 0.f);
        }
        __half2 o01 = __floats2half2_rn(v[0], v[1]);
        __half2 o23 = __floats2half2_rn(v[2], v[3]);
        __half2 o45 = __floats2half2_rn(v[4], v[5]);
        __half2 o67 = __floats2half2_rn(v[6], v[7]);
        uint4 ou;
        ou.x = *(unsigned*)&o01; ou.y = *(unsigned*)&o23;
        ou.z = *(unsigned*)&o45; ou.w = *(unsigned*)&o67;
        *(uint4*)&out[(size_t)node * 128 + c0] = ou;
    }
}

// ================= CSR aggregation, CT=32 (layers 1, 3) =================
// One 16-lane group per node. Decoupled pipeline: records 3 ahead, xl gather
// issued from a src id loaded 2 iterations earlier.
template <int HC, bool RELU, typename OUT>
__global__ __launch_bounds__(256) void agg32_kernel(
    const int* __restrict__ rowptr, const ERec* __restrict__ csr,
    const __half* __restrict__ xl, const __half* __restrict__ xr,
    const float* __restrict__ We,   // [8,32]
    const float* __restrict__ att,  // flat [32]
    const float* __restrict__ bias, // [32]
    OUT* __restrict__ out, int n) {
    int tid = threadIdx.x;
    int node = (blockIdx.x * 256 + tid) >> 4;   // one 16-lane group per node
    int q = tid & 15;
    if (node >= n) return;
    int c0 = 2 * q;
    h2 wc0[4], wc1[4];
#pragma unroll
    for (int k = 0; k < 4; ++k) {
        wc0[k] = h2{(_Float16)We[(2 * k) * 32 + c0], (_Float16)We[(2 * k + 1) * 32 + c0]};
        wc1[k] = h2{(_Float16)We[(2 * k) * 32 + c0 + 1], (_Float16)We[(2 * k + 1) * 32 + c0 + 1]};
    }
    float att0 = att[c0], att1 = att[c0 + 1];
    int beg = rowptr[node], end = rowptr[node + 1];
    h2 xrh = bch2(*(const unsigned*)&xr[(size_t)node * 32 + c0]);
    float xrc0 = (float)xrh.x, xrc1 = (float)xrh.y;
    float num0 = 0.f, num1 = 0.f, den = 0.f;

    int j = beg;
    uint4 u0, u1, u2; int s0, s1, s2; unsigned x0;
    if (j < end)     { u0 = *(const uint4*)csr[j].ea;     s0 = csr[j].src; }
    if (j + 1 < end) { u1 = *(const uint4*)csr[j + 1].ea; s1 = csr[j + 1].src; }
    if (j + 2 < end) { u2 = *(const uint4*)csr[j + 2].ea; s2 = csr[j + 2].src; }
    if (j < end)     x0 = *(const unsigned*)&xl[(size_t)s0 * 32 + c0];
    while (j < end) {
        uint4 uT; int sT; unsigned xT;
        if (j + 3 < end) { uT = *(const uint4*)csr[j + 3].ea; sT = csr[j + 3].src; }
        if (j + 1 < end) { xT = *(const unsigned*)&xl[(size_t)s1 * 32 + c0]; } // s1: 2 iters old
        h2 e0 = bch2(u0.x), e1 = bch2(u0.y), e2 = bch2(u0.z), e3 = bch2(u0.w);
        h2 xlh = bch2(x0);
        float xls0 = (float)xlh.x, xls1 = (float)xlh.y;
        float m0 = xls0 + xrc0, m1 = xls1 + xrc1;
        m0 = fdot2f(e0, wc0[0], m0); m0 = fdot2f(e1, wc0[1], m0);
        m0 = fdot2f(e2, wc0[2], m0); m0 = fdot2f(e3, wc0[3], m0);
        m1 = fdot2f(e0, wc1[0], m1); m1 = fdot2f(e1, wc1[1], m1);
        m1 = fdot2f(e2, wc1[2], m1); m1 = fdot2f(e3, wc1[3], m1);
        float s0v = fmaxf(m0, 0.f) + NEG_SLOPE * fminf(m0, 0.f);
        float s1v = fmaxf(m1, 0.f) + NEG_SLOPE * fminf(m1, 0.f);
        float p = fmaf(s0v, att0, s1v * att1);
#pragma unroll
        for (int off = HC / 4; off > 0; off >>= 1) p += __shfl_xor(p, off); // head group
        float wgt = __expf(p);
        num0 = fmaf(wgt, xls0, num0);
        num1 = fmaf(wgt, xls1, num1);
        den += wgt;
        j += 1;
        u0 = u1; u1 = u2; u2 = uT;
        s1 = s2; s2 = sT;
        x0 = xT;
    }
    float inv = 1.f / den;
    float v0 = num0 * inv + bias[c0];
    float v1 = num1 * inv + bias[c0 + 1];
    if (RELU) { v0 = fmaxf(v0, 0.f); v1 = fmaxf(v1, 0.f); }
    if constexpr (sizeof(OUT) == 2) {
        __half2 o = __floats2half2_rn(v0, v1);
        *(__half2*)&out[(size_t)node * 32 + c0] = o;
    } else {
        float2 o; o.x = v0; o.y = v1;
        *(float2*)&out[(size_t)node * 32 + c0] = o;
    }
}

extern "C" void kernel_launch(void* const* d_in, const int* in_sizes, int n_in,
                              void* d_out, int out_size, void* d_ws, size_t ws_size,
                              hipStream_t stream) {
    const float* x    = (const float*)d_in[0];
    const int* ei     = (const int*)d_in[1];
    const float* eatt = (const float*)d_in[2];
    const float* Wl1 = (const float*)d_in[3],  *bl1 = (const float*)d_in[4];
    const float* Wr1 = (const float*)d_in[5],  *br1 = (const float*)d_in[6];
    const float* We1 = (const float*)d_in[7],  *att1 = (const float*)d_in[8];
    const float* b1  = (const float*)d_in[9];
    const float* Wl2 = (const float*)d_in[10], *bl2 = (const float*)d_in[11];
    const float* Wr2 = (const float*)d_in[12], *br2 = (const float*)d_in[13];
    const float* We2 = (const float*)d_in[14], *att2 = (const float*)d_in[15];
    const float* b2  = (const float*)d_in[16], *Rw2 = (const float*)d_in[17];
    const float* Wl3 = (const float*)d_in[18], *bl3 = (const float*)d_in[19];
    const float* Wr3 = (const float*)d_in[20], *br3 = (const float*)d_in[21];
    const float* We3 = (const float*)d_in[22], *att3 = (const float*)d_in[23];
    const float* b3  = (const float*)d_in[24];

    const int* srcp = ei;
    const int* dstp = ei + EE;

    // ---- workspace layout (~70 MB) ----
    char* w = (char*)d_ws;
    size_t off = 0;
    auto alloc = [&](size_t bytes) { char* p = w + off; off += (bytes + 255) & ~size_t(255); return p; };
    int*    rowcnt   = (int*)alloc((size_t)NN * 4);
    int*    rowptr   = (int*)alloc((size_t)(NN + 1) * 4);
    int*    cursor   = (int*)alloc((size_t)NN * 4);
    int*    blocksum = (int*)alloc(256 * 4);
    ERec*   csr      = (ERec*)alloc((size_t)(EE + NN) * sizeof(ERec));
    __half* xlbuf    = (__half*)alloc((size_t)NN * 128 * 2);
    __half* xrbuf    = (__half*)alloc((size_t)NN * 128 * 2);
    __half* hA       = (__half*)alloc((size_t)NN * 32 * 2);
    __half* hB       = (__half*)alloc((size_t)NN * 128 * 2);

    int nb = cdiv(NN, 256);

    // ---- CSR build (self-loop in front slot of each row) ----
    hipMemsetAsync(rowcnt, 0, (size_t)NN * 4, stream);
    hist_kernel<<<cdiv(EE / 4, 256), 256, 0, stream>>>((const int4*)dstp, rowcnt, EE / 4);
    scana_kernel<<<nb, 256, 0, stream>>>(rowcnt, blocksum, NN);
    scanb_kernel<<<nb, 256, 0, stream>>>(rowcnt, blocksum, nb, rowptr, cursor, csr, NN);
    scatter_kernel<<<cdiv(EE, 256), 256, 0, stream>>>(
        srcp, dstp, eatt, cursor, csr, EE);

    // ---- fused: loop_sea + node_linear layer 1 ----
    constexpr int NB1 = (NN + 7) / 8;
    int nb_ls = cdiv(NN, 4);
    fused_nl1_loopsea_kernel<NB1><<<NB1 + nb_ls, 256, 0, stream>>>(
        x, Wl1, bl1, Wr1, br1, xlbuf, xrbuf, rowptr, csr, NN);

    // ---- layer 1 aggregation: H=4, C=8 (CT=32) ----
    agg32_kernel<8, true, __half><<<cdiv(NN, 16), 256, 0, stream>>>(
        rowptr, csr, xlbuf, xrbuf, We1, att1, b1, hA, NN);

    // ---- layer 2: IN=32 -> H=4, C=32 (CT=128), residual fused into nlh2 ----
    nlh2_res_kernel<32><<<cdiv(NN, 32), 256, 0, stream>>>(
        hA, Wl2, bl2, Wr2, br2, Rw2, b2, xlbuf, xrbuf, hB, NN);
    agg128_kernel<true, true><<<cdiv(NN, 4), 256, 0, stream>>>(
        rowptr, csr, xlbuf, xrbuf, We2, att2, b2, hB, NN);

    // ---- layer 3: IN=128 -> H=1, C=32 (CT=32) ----
    node_linear_h_kernel<128, 32, 64><<<cdiv(NN, 64), 256, 0, stream>>>(
        hB, Wl3, bl3, Wr3, br3, xlbuf, xrbuf, NN);
    agg32_kernel<32, false, float><<<cdiv(NN, 16), 256, 0, stream>>>(
        rowptr, csr, xlbuf, xrbuf, We3, att3, b3,
        (float*)d_out, NN);
}

// Round 10
// 418.846 us; speedup vs baseline: 1.0042x; 1.0042x over previous
//
#include <hip/hip_runtime.h>
#include <hip/hip_fp16.h>

#define NEG_SLOPE 0.2f

constexpr int NN = 50000;   // nodes
constexpr int EE = 800000;  // edges (before self loops)

static inline int cdiv(int a, int b) { return (a + b - 1) / b; }

typedef _Float16 h2 __attribute__((ext_vector_type(2)));

#if __has_builtin(__builtin_amdgcn_fdot2)
static __device__ inline float fdot2f(h2 a, h2 b, float c) {
    return __builtin_amdgcn_fdot2(a, b, c, false);
}
#else
static __device__ inline float fdot2f(h2 a, h2 b, float c) {
    return c + (float)a.x * (float)b.x + (float)a.y * (float)b.y;
}
#endif

static __device__ inline h2 bch2(unsigned u) { return __builtin_bit_cast(h2, u); }

// 32-byte edge record: fp16 edge attrs + src id (always within one 64B line)
struct __align__(16) ERec {
    __half ea[8];   // 16 B
    int src;        // 4 B
    int pad[3];     // 12 B
};

// ================= CSR build =================
__global__ void hist_kernel(const int4* __restrict__ dst4, int* __restrict__ rowcnt, int E4) {
    int t = blockIdx.x * blockDim.x + threadIdx.x;
    if (t >= E4) return;
    int4 d = dst4[t];
    atomicAdd(&rowcnt[d.x], 1);
    atomicAdd(&rowcnt[d.y], 1);
    atomicAdd(&rowcnt[d.z], 1);
    atomicAdd(&rowcnt[d.w], 1);
}

__global__ void scana_kernel(const int* __restrict__ cnt, int* __restrict__ blocksum, int n) {
    __shared__ int s[256];
    int t = threadIdx.x, g = blockIdx.x * 256 + t;
    s[t] = (g < n) ? cnt[g] + 1 : 0;
    __syncthreads();
    for (int off = 128; off > 0; off >>= 1) {
        if (t < off) s[t] += s[t + off];
        __syncthreads();
    }
    if (t == 0) blocksum[blockIdx.x] = s[0];
}

__global__ void scanb_kernel(const int* __restrict__ cnt, const int* __restrict__ blocksum,
                             int nbk, int* __restrict__ rowptr, int* __restrict__ cursor,
                             ERec* __restrict__ csr, int n) {
    __shared__ int bs[256];
    __shared__ int s[256];
    int t = threadIdx.x;
    bs[t] = (t < nbk) ? blocksum[t] : 0;
    __syncthreads();
    for (int off = 1; off < 256; off <<= 1) {
        int tv = (t >= off) ? bs[t - off] : 0; __syncthreads();
        bs[t] += tv; __syncthreads();
    }
    int blockoff = (blockIdx.x > 0) ? bs[blockIdx.x - 1] : 0;
    int g = blockIdx.x * 256 + t;
    int val = (g < n) ? cnt[g] + 1 : 0;
    s[t] = val; __syncthreads();
    for (int off = 1; off < 256; off <<= 1) {
        int tv = (t >= off) ? s[t - off] : 0; __syncthreads();
        s[t] += tv; __syncthreads();
    }
    if (g >= n) return;
    int incl = s[t] + blockoff;
    rowptr[g + 1] = incl;
    int beg = incl - val;
    cursor[g] = beg + 1;          // slot `beg` reserved for the self loop
    csr[beg].src = g;             // self-loop source
    if (g == 0) rowptr[0] = 0;
}

__global__ void scatter_kernel(const int* __restrict__ src, const int* __restrict__ dst,
                               const float* __restrict__ eattr,
                               int* __restrict__ cursor, ERec* __restrict__ csr, int E) {
    int t = blockIdx.x * blockDim.x + threadIdx.x;
    if (t >= E) return;
    int d = dst[t];
    int pos = atomicAdd(&cursor[d], 1);
    const float4* ea4 = (const float4*)(eattr + (size_t)t * 8);
    float4 a = ea4[0], b = ea4[1];
    __half2 h0 = __floats2half2_rn(a.x, a.y);
    __half2 h1 = __floats2half2_rn(a.z, a.w);
    __half2 h2v = __floats2half2_rn(b.x, b.y);
    __half2 h3 = __floats2half2_rn(b.z, b.w);
    uint4 u;
    u.x = *(unsigned*)&h0; u.y = *(unsigned*)&h1;
    u.z = *(unsigned*)&h2v; u.w = *(unsigned*)&h3;
    ERec* r = &csr[pos];
    *(uint4*)r->ea = u;
    r->src = src[t];
}

// ======= fused: node_linear layer-1 (blocks < NB1) + loop_sea (rest) =========
template <int NB1>
__global__ __launch_bounds__(256) void fused_nl1_loopsea_kernel(
    const float* __restrict__ x,
    const float* __restrict__ Wl, const float* __restrict__ bl,
    const float* __restrict__ Wr, const float* __restrict__ br,
    __half* __restrict__ xl, __half* __restrict__ xr,
    const int* __restrict__ rowptr, ERec* __restrict__ csr, int n) {
    constexpr int K = 16, CT = 32, NPB = 8;
    __shared__ float Wls[K * CT];
    __shared__ float Wrs[K * CT];
    __shared__ float xs[NPB * K];
    int tid = threadIdx.x;
    if (blockIdx.x < NB1) {
        int ty = tid >> 5, c = tid & 31;
        for (int i = tid; i < K * CT; i += 256) { Wls[i] = Wl[i]; Wrs[i] = Wr[i]; }
        int node0 = blockIdx.x * NPB;
        for (int i = tid; i < NPB * K; i += 256) {
            int nd = node0 + i / K;
            xs[i] = (nd < n) ? x[(size_t)node0 * K + i] : 0.f;
        }
        __syncthreads();
        int node = node0 + ty;
        if (node >= n) return;
        float aL = bl[c], aR = br[c];
        const float* xrow = &xs[ty * K];
        for (int k = 0; k < K; ++k) {
            float xv = xrow[k];
            aL = fmaf(xv, Wls[k * CT + c], aL);
            aR = fmaf(xv, Wrs[k * CT + c], aR);
        }
        xl[(size_t)node * CT + c] = __float2half(aL);
        xr[(size_t)node * CT + c] = __float2half(aR);
    } else {
        int wave = ((blockIdx.x - NB1) * 256 + tid) >> 6;
        int lane = tid & 63;
        if (wave >= n) return;
        int beg = rowptr[wave], end = rowptr[wave + 1];
        int k = lane & 7, j0 = lane >> 3;
        float s = 0.f;
        for (int j = beg + 1 + j0; j < end; j += 8)
            s += __half2float(csr[j].ea[k]);
        s += __shfl_xor(s, 8); s += __shfl_xor(s, 16); s += __shfl_xor(s, 32);
        int cnt = end - beg - 1;
        if (lane < 8) csr[beg].ea[lane] = __float2half(s / fmaxf((float)cnt, 1.f));
    }
}

// ======= node linear (fp16 input, fp16 LDS weights, fdot2, node-loop) ========
template <int K, int CT, int NPB>
__global__ __launch_bounds__(256) void node_linear_h_kernel(
    const __half* __restrict__ x,
    const float* __restrict__ Wl, const float* __restrict__ bl,
    const float* __restrict__ Wr, const float* __restrict__ br,
    __half* __restrict__ xl, __half* __restrict__ xr, int n) {
    constexpr int K2 = K / 2;
    constexpr int TS = 256 / CT;     // node-slots per pass
    __shared__ h2 Wls[K2 * CT];
    __shared__ h2 Wrs[K2 * CT];
    __shared__ h2 xs[NPB * K2];
    int tid = threadIdx.x;
    for (int i = tid; i < K2 * CT; i += 256) {
        int k2 = i / CT, c = i % CT;
        Wls[i] = h2{(_Float16)Wl[(2 * k2) * CT + c], (_Float16)Wl[(2 * k2 + 1) * CT + c]};
        Wrs[i] = h2{(_Float16)Wr[(2 * k2) * CT + c], (_Float16)Wr[(2 * k2 + 1) * CT + c]};
    }
    int node0 = blockIdx.x * NPB;
    const unsigned* xg = (const unsigned*)(x + (size_t)node0 * K);
    for (int i = tid; i < NPB * K2; i += 256) {
        int nd = node0 + i / K2;
        unsigned u = (nd < n) ? xg[i] : 0u;
        xs[i] = bch2(u);
    }
    __syncthreads();
    int c = tid % CT, ty = tid / CT;
    int bound = (node0 + NPB < n) ? NPB : (n - node0);
    for (int local = ty; local < bound; local += TS) {
        int node = node0 + local;
        float aL = bl[c], aR = br[c];
        const h2* xrow = &xs[local * K2];
        for (int k = 0; k < K2; ++k) {
            h2 xv = xrow[k];
            aL = fdot2f(xv, Wls[k * CT + c], aL);
            aR = fdot2f(xv, Wrs[k * CT + c], aR);
        }
        xl[(size_t)node * CT + c] = __float2half(aL);
        xr[(size_t)node * CT + c] = __float2half(aR);
    }
}

// ======= layer-2 node linear + residual: xl, xr, and res = b2 + hA @ Rw =======
template <int NPB>
__global__ __launch_bounds__(256) void nlh2_res_kernel(
    const __half* __restrict__ x,   // hA [N,32]
    const float* __restrict__ Wl, const float* __restrict__ bl,
    const float* __restrict__ Wr, const float* __restrict__ br,
    const float* __restrict__ Rw,   // [32,128] fp32
    const float* __restrict__ b2,   // [128]
    __half* __restrict__ xl, __half* __restrict__ xr,
    __half* __restrict__ res, int n) {
    constexpr int K = 32, CT = 128, K2 = K / 2;
    __shared__ h2 Wls[K2 * CT];
    __shared__ h2 Wrs[K2 * CT];
    __shared__ float Rws[K * CT];
    __shared__ h2 xs[NPB * K2];
    int tid = threadIdx.x;
    for (int i = tid; i < K2 * CT; i += 256) {
        int k2 = i / CT, c = i % CT;
        Wls[i] = h2{(_Float16)Wl[(2 * k2) * CT + c], (_Float16)Wl[(2 * k2 + 1) * CT + c]};
        Wrs[i] = h2{(_Float16)Wr[(2 * k2) * CT + c], (_Float16)Wr[(2 * k2 + 1) * CT + c]};
    }
    for (int i = tid; i < K * CT; i += 256) Rws[i] = Rw[i];
    int node0 = blockIdx.x * NPB;
    const unsigned* xg = (const unsigned*)(x + (size_t)node0 * K);
    for (int i = tid; i < NPB * K2; i += 256) {
        int nd = node0 + i / K2;
        unsigned u = (nd < n) ? xg[i] : 0u;
        xs[i] = bch2(u);
    }
    __syncthreads();
    int c = tid & 127, ty = tid >> 7;   // 2 node-slots
    int bound = (node0 + NPB < n) ? NPB : (n - node0);
    for (int local = ty; local < bound; local += 2) {
        int node = node0 + local;
        float aL = bl[c], aR = br[c], aS = b2[c];
        const h2* xrow = &xs[local * K2];
        for (int k = 0; k < K2; ++k) {
            h2 xv = xrow[k];
            aL = fdot2f(xv, Wls[k * CT + c], aL);
            aR = fdot2f(xv, Wrs[k * CT + c], aR);
            aS = fmaf((float)xv.x, Rws[(2 * k) * CT + c], aS);
            aS = fmaf((float)xv.y, Rws[(2 * k + 1) * CT + c], aS);
        }
        xl[(size_t)node * CT + c] = __float2half(aL);
        xr[(size_t)node * CT + c] = __float2half(aR);
        res[(size_t)node * CT + c] = __float2half(aS);
    }
}

// ================= CSR aggregation, CT=128 (layer 2) =================
// One wave per node; 2 edge-chains per wave (32 lanes each, 4 ch/lane) —
// the validated 74.5us geometry — with the inner loop unrolled 2x:
// each iteration processes 2 edges per chain (4/wave), halving loop-control
// and pipeline-shift overhead. Decoupling kept: the xl gather for an edge
// uses a src id whose record load was issued 2 basic-iterations earlier.
// RES: residual (b2 + hA@Rw2) pre-written into `out` by nlh2_res_kernel.
template <bool RELU, bool RES>
__global__ __launch_bounds__(256) void agg128_kernel(
    const int* __restrict__ rowptr, const ERec* __restrict__ csr,
    const __half* __restrict__ xl, const __half* __restrict__ xr,
    const float* __restrict__ We,   // [8,128]
    const float* __restrict__ att,  // flat [128]
    const float* __restrict__ bias, // [128] (used only when !RES)
    __half* __restrict__ out, int n) {
    int tid = threadIdx.x;
    int node = (blockIdx.x * 256 + tid) >> 6;
    int lane = tid & 63;
    if (node >= n) return;
    int sub = lane >> 5, cl = lane & 31;
    int c0 = 4 * cl;
    h2 wch[4][4];
    float attc[4];
#pragma unroll
    for (int c = 0; c < 4; ++c) {
        attc[c] = att[c0 + c];
#pragma unroll
        for (int k = 0; k < 4; ++k)
            wch[c][k] = h2{(_Float16)We[(2 * k) * 128 + c0 + c],
                           (_Float16)We[(2 * k + 1) * 128 + c0 + c]};
    }
    int beg = rowptr[node], end = rowptr[node + 1];
    uint2 xru = *(const uint2*)&xr[(size_t)node * 128 + c0];
    h2 xr01 = bch2(xru.x), xr23 = bch2(xru.y);
    float xrc[4] = {(float)xr01.x, (float)xr01.y, (float)xr23.x, (float)xr23.y};
    float num[4] = {0.f, 0.f, 0.f, 0.f};
    float den = 0.f;

    int j = beg + sub;
    // pipeline state: records for edges j, j+2 (current pair) and j+4, j+6
    // (next pair, srcs sA/sB held for the next iteration's gathers);
    // x0/x1 = xl fragments for the current pair.
    uint4 u0, u1, u2, u3; int sA, sB; uint2 x0, x1;
    if (j < end) {
        u0 = *(const uint4*)csr[j].ea;
        int s_ = csr[j].src;
        x0 = *(const uint2*)&xl[(size_t)s_ * 128 + c0];
    }
    if (j + 2 < end) {
        u1 = *(const uint4*)csr[j + 2].ea;
        int s_ = csr[j + 2].src;
        x1 = *(const uint2*)&xl[(size_t)s_ * 128 + c0];
    }
    if (j + 4 < end) { u2 = *(const uint4*)csr[j + 4].ea; sA = csr[j + 4].src; }
    if (j + 6 < end) { u3 = *(const uint4*)csr[j + 6].ea; sB = csr[j + 6].src; }
    while (j < end) {
        uint4 uT0, uT1; int sT0, sT1; uint2 xT0, xT1;
        if (j + 8 < end)  { uT0 = *(const uint4*)csr[j + 8].ea;  sT0 = csr[j + 8].src; }
        if (j + 10 < end) { uT1 = *(const uint4*)csr[j + 10].ea; sT1 = csr[j + 10].src; }
        if (j + 4 < end)  { xT0 = *(const uint2*)&xl[(size_t)sA * 128 + c0]; } // sA: 2 iters old
        if (j + 6 < end)  { xT1 = *(const uint2*)&xl[(size_t)sB * 128 + c0]; } // sB: 2 iters old
        // ---- edge j ----
        {
            h2 e0 = bch2(u0.x), e1 = bch2(u0.y), e2 = bch2(u0.z), e3 = bch2(u0.w);
            h2 xl01 = bch2(x0.x), xl23 = bch2(x0.y);
            float xls[4] = {(float)xl01.x, (float)xl01.y, (float)xl23.x, (float)xl23.y};
            float p = 0.f;
#pragma unroll
            for (int c = 0; c < 4; ++c) {
                float m = xls[c] + xrc[c];
                m = fdot2f(e0, wch[c][0], m); m = fdot2f(e1, wch[c][1], m);
                m = fdot2f(e2, wch[c][2], m); m = fdot2f(e3, wch[c][3], m);
                float sv = fmaxf(m, 0.f) + NEG_SLOPE * fminf(m, 0.f);
                p = fmaf(sv, attc[c], p);
            }
            p += __shfl_xor(p, 1); p += __shfl_xor(p, 2); p += __shfl_xor(p, 4);
            float wgt = __expf(p);
#pragma unroll
            for (int c = 0; c < 4; ++c) num[c] = fmaf(wgt, xls[c], num[c]);
            den += wgt;
        }
        // ---- edge j+2 (guard uniform within a 32-lane chain) ----
        if (j + 2 < end) {
            h2 e0 = bch2(u1.x), e1 = bch2(u1.y), e2 = bch2(u1.z), e3 = bch2(u1.w);
            h2 xl01 = bch2(x1.x), xl23 = bch2(x1.y);
            float xls[4] = {(float)xl01.x, (float)xl01.y, (float)xl23.x, (float)xl23.y};
            float p = 0.f;
#pragma unroll
            for (int c = 0; c < 4; ++c) {
                float m = xls[c] + xrc[c];
                m = fdot2f(e0, wch[c][0], m); m = fdot2f(e1, wch[c][1], m);
                m = fdot2f(e2, wch[c][2], m); m = fdot2f(e3, wch[c][3], m);
                float sv = fmaxf(m, 0.f) + NEG_SLOPE * fminf(m, 0.f);
                p = fmaf(sv, attc[c], p);
            }
            p += __shfl_xor(p, 1); p += __shfl_xor(p, 2); p += __shfl_xor(p, 4);
            float wgt = __expf(p);
#pragma unroll
            for (int c = 0; c < 4; ++c) num[c] = fmaf(wgt, xls[c], num[c]);
            den += wgt;
        }
        j += 4;
        u0 = u2; u1 = u3; u2 = uT0; u3 = uT1;
        sA = sT0; sB = sT1;
        x0 = xT0; x1 = xT1;
    }
    // combine the two 32-lane chains
#pragma unroll
    for (int c = 0; c < 4; ++c) num[c] += __shfl_xor(num[c], 32);
    den += __shfl_xor(den, 32);
    if (sub == 0) {
        float inv = 1.f / den;
        float base[4];
        if (RES) {
            uint2 ru = *(const uint2*)&out[(size_t)node * 128 + c0];
            h2 r01 = bch2(ru.x), r23 = bch2(ru.y);
            base[0] = (float)r01.x; base[1] = (float)r01.y;
            base[2] = (float)r23.x; base[3] = (float)r23.y;
        } else {
#pragma unroll
            for (int c = 0; c < 4; ++c) base[c] = bias[c0 + c];
        }
        float v[4];
#pragma unroll
        for (int c = 0; c < 4; ++c) v[c] = fmaf(num[c], inv, base[c]);
        if (RELU) {
#pragma unroll
            for (int c = 0; c < 4; ++c) v[c] = fmaxf(v[c], 0.f);
        }
        __half2 o01 = __floats2half2_rn(v[0], v[1]);
        __half2 o23 = __floats2half2_rn(v[2], v[3]);
        uint2 ou; ou.x = *(unsigned*)&o01; ou.y = *(unsigned*)&o23;
        *(uint2*)&out[(size_t)node * 128 + c0] = ou;
    }
}

// ================= CSR aggregation, CT=32 (layers 1, 3) =================
// One 16-lane group per node. Decoupled pipeline: records 3 ahead, xl gather
// issued from a src id loaded 2 iterations earlier.
template <int HC, bool RELU, typename OUT>
__global__ __launch_bounds__(256) void agg32_kernel(
    const int* __restrict__ rowptr, const ERec* __restrict__ csr,
    const __half* __restrict__ xl, const __half* __restrict__ xr,
    const float* __restrict__ We,   // [8,32]
    const float* __restrict__ att,  // flat [32]
    const float* __restrict__ bias, // [32]
    OUT* __restrict__ out, int n) {
    int tid = threadIdx.x;
    int node = (blockIdx.x * 256 + tid) >> 4;   // one 16-lane group per node
    int q = tid & 15;
    if (node >= n) return;
    int c0 = 2 * q;
    h2 wc0[4], wc1[4];
#pragma unroll
    for (int k = 0; k < 4; ++k) {
        wc0[k] = h2{(_Float16)We[(2 * k) * 32 + c0], (_Float16)We[(2 * k + 1) * 32 + c0]};
        wc1[k] = h2{(_Float16)We[(2 * k) * 32 + c0 + 1], (_Float16)We[(2 * k + 1) * 32 + c0 + 1]};
    }
    float att0 = att[c0], att1 = att[c0 + 1];
    int beg = rowptr[node], end = rowptr[node + 1];
    h2 xrh = bch2(*(const unsigned*)&xr[(size_t)node * 32 + c0]);
    float xrc0 = (float)xrh.x, xrc1 = (float)xrh.y;
    float num0 = 0.f, num1 = 0.f, den = 0.f;

    int j = beg;
    uint4 u0, u1, u2; int s0, s1, s2; unsigned x0;
    if (j < end)     { u0 = *(const uint4*)csr[j].ea;     s0 = csr[j].src; }
    if (j + 1 < end) { u1 = *(const uint4*)csr[j + 1].ea; s1 = csr[j + 1].src; }
    if (j + 2 < end) { u2 = *(const uint4*)csr[j + 2].ea; s2 = csr[j + 2].src; }
    if (j < end)     x0 = *(const unsigned*)&xl[(size_t)s0 * 32 + c0];
    while (j < end) {
        uint4 uT; int sT; unsigned xT;
        if (j + 3 < end) { uT = *(const uint4*)csr[j + 3].ea; sT = csr[j + 3].src; }
        if (j + 1 < end) { xT = *(const unsigned*)&xl[(size_t)s1 * 32 + c0]; } // s1: 2 iters old
        h2 e0 = bch2(u0.x), e1 = bch2(u0.y), e2 = bch2(u0.z), e3 = bch2(u0.w);
        h2 xlh = bch2(x0);
        float xls0 = (float)xlh.x, xls1 = (float)xlh.y;
        float m0 = xls0 + xrc0, m1 = xls1 + xrc1;
        m0 = fdot2f(e0, wc0[0], m0); m0 = fdot2f(e1, wc0[1], m0);
        m0 = fdot2f(e2, wc0[2], m0); m0 = fdot2f(e3, wc0[3], m0);
        m1 = fdot2f(e0, wc1[0], m1); m1 = fdot2f(e1, wc1[1], m1);
        m1 = fdot2f(e2, wc1[2], m1); m1 = fdot2f(e3, wc1[3], m1);
        float s0v = fmaxf(m0, 0.f) + NEG_SLOPE * fminf(m0, 0.f);
        float s1v = fmaxf(m1, 0.f) + NEG_SLOPE * fminf(m1, 0.f);
        float p = fmaf(s0v, att0, s1v * att1);
#pragma unroll
        for (int off = HC / 4; off > 0; off >>= 1) p += __shfl_xor(p, off); // head group
        float wgt = __expf(p);
        num0 = fmaf(wgt, xls0, num0);
        num1 = fmaf(wgt, xls1, num1);
        den += wgt;
        j += 1;
        u0 = u1; u1 = u2; u2 = uT;
        s1 = s2; s2 = sT;
        x0 = xT;
    }
    float inv = 1.f / den;
    float v0 = num0 * inv + bias[c0];
    float v1 = num1 * inv + bias[c0 + 1];
    if (RELU) { v0 = fmaxf(v0, 0.f); v1 = fmaxf(v1, 0.f); }
    if constexpr (sizeof(OUT) == 2) {
        __half2 o = __floats2half2_rn(v0, v1);
        *(__half2*)&out[(size_t)node * 32 + c0] = o;
    } else {
        float2 o; o.x = v0; o.y = v1;
        *(float2*)&out[(size_t)node * 32 + c0] = o;
    }
}

extern "C" void kernel_launch(void* const* d_in, const int* in_sizes, int n_in,
                              void* d_out, int out_size, void* d_ws, size_t ws_size,
                              hipStream_t stream) {
    const float* x    = (const float*)d_in[0];
    const int* ei     = (const int*)d_in[1];
    const float* eatt = (const float*)d_in[2];
    const float* Wl1 = (const float*)d_in[3],  *bl1 = (const float*)d_in[4];
    const float* Wr1 = (const float*)d_in[5],  *br1 = (const float*)d_in[6];
    const float* We1 = (const float*)d_in[7],  *att1 = (const float*)d_in[8];
    const float* b1  = (const float*)d_in[9];
    const float* Wl2 = (const float*)d_in[10], *bl2 = (const float*)d_in[11];
    const float* Wr2 = (const float*)d_in[12], *br2 = (const float*)d_in[13];
    const float* We2 = (const float*)d_in[14], *att2 = (const float*)d_in[15];
    const float* b2  = (const float*)d_in[16], *Rw2 = (const float*)d_in[17];
    const float* Wl3 = (const float*)d_in[18], *bl3 = (const float*)d_in[19];
    const float* Wr3 = (const float*)d_in[20], *br3 = (const float*)d_in[21];
    const float* We3 = (const float*)d_in[22], *att3 = (const float*)d_in[23];
    const float* b3  = (const float*)d_in[24];

    const int* srcp = ei;
    const int* dstp = ei + EE;

    // ---- workspace layout (~70 MB) ----
    char* w = (char*)d_ws;
    size_t off = 0;
    auto alloc = [&](size_t bytes) { char* p = w + off; off += (bytes + 255) & ~size_t(255); return p; };
    int*    rowcnt   = (int*)alloc((size_t)NN * 4);
    int*    rowptr   = (int*)alloc((size_t)(NN + 1) * 4);
    int*    cursor   = (int*)alloc((size_t)NN * 4);
    int*    blocksum = (int*)alloc(256 * 4);
    ERec*   csr      = (ERec*)alloc((size_t)(EE + NN) * sizeof(ERec));
    __half* xlbuf    = (__half*)alloc((size_t)NN * 128 * 2);
    __half* xrbuf    = (__half*)alloc((size_t)NN * 128 * 2);
    __half* hA       = (__half*)alloc((size_t)NN * 32 * 2);
    __half* hB       = (__half*)alloc((size_t)NN * 128 * 2);

    int nb = cdiv(NN, 256);

    // ---- CSR build (self-loop in front slot of each row) ----
    hipMemsetAsync(rowcnt, 0, (size_t)NN * 4, stream);
    hist_kernel<<<cdiv(EE / 4, 256), 256, 0, stream>>>((const int4*)dstp, rowcnt, EE / 4);
    scana_kernel<<<nb, 256, 0, stream>>>(rowcnt, blocksum, NN);
    scanb_kernel<<<nb, 256, 0, stream>>>(rowcnt, blocksum, nb, rowptr, cursor, csr, NN);
    scatter_kernel<<<cdiv(EE, 256), 256, 0, stream>>>(
        srcp, dstp, eatt, cursor, csr, EE);

    // ---- fused: loop_sea + node_linear layer 1 ----
    constexpr int NB1 = (NN + 7) / 8;
    int nb_ls = cdiv(NN, 4);
    fused_nl1_loopsea_kernel<NB1><<<NB1 + nb_ls, 256, 0, stream>>>(
        x, Wl1, bl1, Wr1, br1, xlbuf, xrbuf, rowptr, csr, NN);

    // ---- layer 1 aggregation: H=4, C=8 (CT=32) ----
    agg32_kernel<8, true, __half><<<cdiv(NN, 16), 256, 0, stream>>>(
        rowptr, csr, xlbuf, xrbuf, We1, att1, b1, hA, NN);

    // ---- layer 2: IN=32 -> H=4, C=32 (CT=128), residual fused into nlh2 ----
    nlh2_res_kernel<32><<<cdiv(NN, 32), 256, 0, stream>>>(
        hA, Wl2, bl2, Wr2, br2, Rw2, b2, xlbuf, xrbuf, hB, NN);
    agg128_kernel<true, true><<<cdiv(NN, 4), 256, 0, stream>>>(
        rowptr, csr, xlbuf, xrbuf, We2, att2, b2, hB, NN);

    // ---- layer 3: IN=128 -> H=1, C=32 (CT=32) ----
    node_linear_h_kernel<128, 32, 64><<<cdiv(NN, 64), 256, 0, stream>>>(
        hB, Wl3, bl3, Wr3, br3, xlbuf, xrbuf, NN);
    agg32_kernel<32, false, float><<<cdiv(NN, 16), 256, 0, stream>>>(
        rowptr, csr, xlbuf, xrbuf, We3, att3, b3,
        (float*)d_out, NN);
}

// Round 11
// 403.331 us; speedup vs baseline: 1.0428x; 1.0385x over previous
//
#include <hip/hip_runtime.h>
#include <hip/hip_fp16.h>

#define NEG_SLOPE 0.2f

constexpr int NN = 50000;   // nodes
constexpr int EE = 800000;  // edges (before self loops)

static inline int cdiv(int a, int b) { return (a + b - 1) / b; }

typedef _Float16 h2 __attribute__((ext_vector_type(2)));

#if __has_builtin(__builtin_amdgcn_fdot2)
static __device__ inline float fdot2f(h2 a, h2 b, float c) {
    return __builtin_amdgcn_fdot2(a, b, c, false);
}
#else
static __device__ inline float fdot2f(h2 a, h2 b, float c) {
    return c + (float)a.x * (float)b.x + (float)a.y * (float)b.y;
}
#endif

static __device__ inline h2 bch2(unsigned u) { return __builtin_bit_cast(h2, u); }

// 32-byte edge record: fp16 edge attrs + src id (always within one 64B line)
struct __align__(16) ERec {
    __half ea[8];   // 16 B
    int src;        // 4 B
    int pad[3];     // 12 B
};

// ================= CSR build =================
__global__ void hist_kernel(const int4* __restrict__ dst4, int* __restrict__ rowcnt, int E4) {
    int t = blockIdx.x * blockDim.x + threadIdx.x;
    if (t >= E4) return;
    int4 d = dst4[t];
    atomicAdd(&rowcnt[d.x], 1);
    atomicAdd(&rowcnt[d.y], 1);
    atomicAdd(&rowcnt[d.z], 1);
    atomicAdd(&rowcnt[d.w], 1);
}

__global__ void scana_kernel(const int* __restrict__ cnt, int* __restrict__ blocksum, int n) {
    __shared__ int s[256];
    int t = threadIdx.x, g = blockIdx.x * 256 + t;
    s[t] = (g < n) ? cnt[g] + 1 : 0;
    __syncthreads();
    for (int off = 128; off > 0; off >>= 1) {
        if (t < off) s[t] += s[t + off];
        __syncthreads();
    }
    if (t == 0) blocksum[blockIdx.x] = s[0];
}

__global__ void scanb_kernel(const int* __restrict__ cnt, const int* __restrict__ blocksum,
                             int nbk, int* __restrict__ rowptr, int* __restrict__ cursor,
                             ERec* __restrict__ csr, int n) {
    __shared__ int bs[256];
    __shared__ int s[256];
    int t = threadIdx.x;
    bs[t] = (t < nbk) ? blocksum[t] : 0;
    __syncthreads();
    for (int off = 1; off < 256; off <<= 1) {
        int tv = (t >= off) ? bs[t - off] : 0; __syncthreads();
        bs[t] += tv; __syncthreads();
    }
    int blockoff = (blockIdx.x > 0) ? bs[blockIdx.x - 1] : 0;
    int g = blockIdx.x * 256 + t;
    int val = (g < n) ? cnt[g] + 1 : 0;
    s[t] = val; __syncthreads();
    for (int off = 1; off < 256; off <<= 1) {
        int tv = (t >= off) ? s[t - off] : 0; __syncthreads();
        s[t] += tv; __syncthreads();
    }
    if (g >= n) return;
    int incl = s[t] + blockoff;
    rowptr[g + 1] = incl;
    int beg = incl - val;
    cursor[g] = beg + 1;          // slot `beg` reserved for the self loop
    csr[beg].src = g;             // self-loop source
    if (g == 0) rowptr[0] = 0;
}

__global__ void scatter_kernel(const int* __restrict__ src, const int* __restrict__ dst,
                               const float* __restrict__ eattr,
                               int* __restrict__ cursor, ERec* __restrict__ csr, int E) {
    int t = blockIdx.x * blockDim.x + threadIdx.x;
    if (t >= E) return;
    int d = dst[t];
    int pos = atomicAdd(&cursor[d], 1);
    const float4* ea4 = (const float4*)(eattr + (size_t)t * 8);
    float4 a = ea4[0], b = ea4[1];
    __half2 h0 = __floats2half2_rn(a.x, a.y);
    __half2 h1 = __floats2half2_rn(a.z, a.w);
    __half2 h2v = __floats2half2_rn(b.x, b.y);
    __half2 h3 = __floats2half2_rn(b.z, b.w);
    uint4 u;
    u.x = *(unsigned*)&h0; u.y = *(unsigned*)&h1;
    u.z = *(unsigned*)&h2v; u.w = *(unsigned*)&h3;
    ERec* r = &csr[pos];
    *(uint4*)r->ea = u;
    r->src = src[t];
}

// ======= fused: node_linear layer-1 (blocks < NB1) + loop_sea (rest) =========
template <int NB1>
__global__ __launch_bounds__(256) void fused_nl1_loopsea_kernel(
    const float* __restrict__ x,
    const float* __restrict__ Wl, const float* __restrict__ bl,
    const float* __restrict__ Wr, const float* __restrict__ br,
    __half* __restrict__ xl, __half* __restrict__ xr,
    const int* __restrict__ rowptr, ERec* __restrict__ csr, int n) {
    constexpr int K = 16, CT = 32, NPB = 8;
    __shared__ float Wls[K * CT];
    __shared__ float Wrs[K * CT];
    __shared__ float xs[NPB * K];
    int tid = threadIdx.x;
    if (blockIdx.x < NB1) {
        int ty = tid >> 5, c = tid & 31;
        for (int i = tid; i < K * CT; i += 256) { Wls[i] = Wl[i]; Wrs[i] = Wr[i]; }
        int node0 = blockIdx.x * NPB;
        for (int i = tid; i < NPB * K; i += 256) {
            int nd = node0 + i / K;
            xs[i] = (nd < n) ? x[(size_t)node0 * K + i] : 0.f;
        }
        __syncthreads();
        int node = node0 + ty;
        if (node >= n) return;
        float aL = bl[c], aR = br[c];
        const float* xrow = &xs[ty * K];
        for (int k = 0; k < K; ++k) {
            float xv = xrow[k];
            aL = fmaf(xv, Wls[k * CT + c], aL);
            aR = fmaf(xv, Wrs[k * CT + c], aR);
        }
        xl[(size_t)node * CT + c] = __float2half(aL);
        xr[(size_t)node * CT + c] = __float2half(aR);
    } else {
        int wave = ((blockIdx.x - NB1) * 256 + tid) >> 6;
        int lane = tid & 63;
        if (wave >= n) return;
        int beg = rowptr[wave], end = rowptr[wave + 1];
        int k = lane & 7, j0 = lane >> 3;
        float s = 0.f;
        for (int j = beg + 1 + j0; j < end; j += 8)
            s += __half2float(csr[j].ea[k]);
        s += __shfl_xor(s, 8); s += __shfl_xor(s, 16); s += __shfl_xor(s, 32);
        int cnt = end - beg - 1;
        if (lane < 8) csr[beg].ea[lane] = __float2half(s / fmaxf((float)cnt, 1.f));
    }
}

// ======= node linear (fp16 input, fp16 LDS weights, fdot2, node-loop) ========
template <int K, int CT, int NPB>
__global__ __launch_bounds__(256) void node_linear_h_kernel(
    const __half* __restrict__ x,
    const float* __restrict__ Wl, const float* __restrict__ bl,
    const float* __restrict__ Wr, const float* __restrict__ br,
    __half* __restrict__ xl, __half* __restrict__ xr, int n) {
    constexpr int K2 = K / 2;
    constexpr int TS = 256 / CT;     // node-slots per pass
    __shared__ h2 Wls[K2 * CT];
    __shared__ h2 Wrs[K2 * CT];
    __shared__ h2 xs[NPB * K2];
    int tid = threadIdx.x;
    for (int i = tid; i < K2 * CT; i += 256) {
        int k2 = i / CT, c = i % CT;
        Wls[i] = h2{(_Float16)Wl[(2 * k2) * CT + c], (_Float16)Wl[(2 * k2 + 1) * CT + c]};
        Wrs[i] = h2{(_Float16)Wr[(2 * k2) * CT + c], (_Float16)Wr[(2 * k2 + 1) * CT + c]};
    }
    int node0 = blockIdx.x * NPB;
    const unsigned* xg = (const unsigned*)(x + (size_t)node0 * K);
    for (int i = tid; i < NPB * K2; i += 256) {
        int nd = node0 + i / K2;
        unsigned u = (nd < n) ? xg[i] : 0u;
        xs[i] = bch2(u);
    }
    __syncthreads();
    int c = tid % CT, ty = tid / CT;
    int bound = (node0 + NPB < n) ? NPB : (n - node0);
    for (int local = ty; local < bound; local += TS) {
        int node = node0 + local;
        float aL = bl[c], aR = br[c];
        const h2* xrow = &xs[local * K2];
        for (int k = 0; k < K2; ++k) {
            h2 xv = xrow[k];
            aL = fdot2f(xv, Wls[k * CT + c], aL);
            aR = fdot2f(xv, Wrs[k * CT + c], aR);
        }
        xl[(size_t)node * CT + c] = __float2half(aL);
        xr[(size_t)node * CT + c] = __float2half(aR);
    }
}

// ======= layer-2 node linear + residual: xl, xr, and res = b2 + hA @ Rw =======
template <int NPB>
__global__ __launch_bounds__(256) void nlh2_res_kernel(
    const __half* __restrict__ x,   // hA [N,32]
    const float* __restrict__ Wl, const float* __restrict__ bl,
    const float* __restrict__ Wr, const float* __restrict__ br,
    const float* __restrict__ Rw,   // [32,128] fp32
    const float* __restrict__ b2,   // [128]
    __half* __restrict__ xl, __half* __restrict__ xr,
    __half* __restrict__ res, int n) {
    constexpr int K = 32, CT = 128, K2 = K / 2;
    __shared__ h2 Wls[K2 * CT];
    __shared__ h2 Wrs[K2 * CT];
    __shared__ float Rws[K * CT];
    __shared__ h2 xs[NPB * K2];
    int tid = threadIdx.x;
    for (int i = tid; i < K2 * CT; i += 256) {
        int k2 = i / CT, c = i % CT;
        Wls[i] = h2{(_Float16)Wl[(2 * k2) * CT + c], (_Float16)Wl[(2 * k2 + 1) * CT + c]};
        Wrs[i] = h2{(_Float16)Wr[(2 * k2) * CT + c], (_Float16)Wr[(2 * k2 + 1) * CT + c]};
    }
    for (int i = tid; i < K * CT; i += 256) Rws[i] = Rw[i];
    int node0 = blockIdx.x * NPB;
    const unsigned* xg = (const unsigned*)(x + (size_t)node0 * K);
    for (int i = tid; i < NPB * K2; i += 256) {
        int nd = node0 + i / K2;
        unsigned u = (nd < n) ? xg[i] : 0u;
        xs[i] = bch2(u);
    }
    __syncthreads();
    int c = tid & 127, ty = tid >> 7;   // 2 node-slots
    int bound = (node0 + NPB < n) ? NPB : (n - node0);
    for (int local = ty; local < bound; local += 2) {
        int node = node0 + local;
        float aL = bl[c], aR = br[c], aS = b2[c];
        const h2* xrow = &xs[local * K2];
        for (int k = 0; k < K2; ++k) {
            h2 xv = xrow[k];
            aL = fdot2f(xv, Wls[k * CT + c], aL);
            aR = fdot2f(xv, Wrs[k * CT + c], aR);
            aS = fmaf((float)xv.x, Rws[(2 * k) * CT + c], aS);
            aS = fmaf((float)xv.y, Rws[(2 * k + 1) * CT + c], aS);
        }
        xl[(size_t)node * CT + c] = __float2half(aL);
        xr[(size_t)node * CT + c] = __float2half(aR);
        res[(size_t)node * CT + c] = __float2half(aS);
    }
}

// ================= CSR aggregation, CT=128 (layer 2) =================
// [REVERTED to the validated 74.5us Round-8 form] One wave per node;
// 2 edge-chains per wave (32 lanes each, 4 ch/lane); decoupled pipeline:
// records prefetched 3 steps ahead; the xl gather for edge i+1 uses a src
// id loaded 2 iterations earlier. 4-chain (R9) and 2x-unroll (R10) both
// regressed: chains are only ~8.5 edges, deeper state eats the prologue.
// RES: residual (b2 + hA@Rw2) pre-written into `out` by nlh2_res_kernel.
template <bool RELU, bool RES>
__global__ __launch_bounds__(256) void agg128_kernel(
    const int* __restrict__ rowptr, const ERec* __restrict__ csr,
    const __half* __restrict__ xl, const __half* __restrict__ xr,
    const float* __restrict__ We,   // [8,128]
    const float* __restrict__ att,  // flat [128]
    const float* __restrict__ bias, // [128] (used only when !RES)
    __half* __restrict__ out, int n) {
    int tid = threadIdx.x;
    int node = (blockIdx.x * 256 + tid) >> 6;
    int lane = tid & 63;
    if (node >= n) return;
    int sub = lane >> 5, cl = lane & 31;
    int c0 = 4 * cl;
    h2 wch[4][4];
    float attc[4];
#pragma unroll
    for (int c = 0; c < 4; ++c) {
        attc[c] = att[c0 + c];
#pragma unroll
        for (int k = 0; k < 4; ++k)
            wch[c][k] = h2{(_Float16)We[(2 * k) * 128 + c0 + c],
                           (_Float16)We[(2 * k + 1) * 128 + c0 + c]};
    }
    int beg = rowptr[node], end = rowptr[node + 1];
    uint2 xru = *(const uint2*)&xr[(size_t)node * 128 + c0];
    h2 xr01 = bch2(xru.x), xr23 = bch2(xru.y);
    float xrc[4] = {(float)xr01.x, (float)xr01.y, (float)xr23.x, (float)xr23.y};
    float num[4] = {0.f, 0.f, 0.f, 0.f};
    float den = 0.f;

    int j = beg + sub;
    // --- pipeline state: records at j, j+2, j+4 in flight; x for edge j ---
    uint4 u0, u1, u2; int s0, s1, s2; uint2 x0;
    if (j < end)     { u0 = *(const uint4*)csr[j].ea;     s0 = csr[j].src; }
    if (j + 2 < end) { u1 = *(const uint4*)csr[j + 2].ea; s1 = csr[j + 2].src; }
    if (j + 4 < end) { u2 = *(const uint4*)csr[j + 4].ea; s2 = csr[j + 4].src; }
    if (j < end)     x0 = *(const uint2*)&xl[(size_t)s0 * 128 + c0];
    while (j < end) {
        uint4 uT; int sT; uint2 xT;
        if (j + 6 < end) { uT = *(const uint4*)csr[j + 6].ea; sT = csr[j + 6].src; }
        if (j + 2 < end) { xT = *(const uint2*)&xl[(size_t)s1 * 128 + c0]; } // s1: 2 iters old
        h2 e0 = bch2(u0.x), e1 = bch2(u0.y), e2 = bch2(u0.z), e3 = bch2(u0.w);
        h2 xl01 = bch2(x0.x), xl23 = bch2(x0.y);
        float xls[4] = {(float)xl01.x, (float)xl01.y, (float)xl23.x, (float)xl23.y};
        float p = 0.f;
#pragma unroll
        for (int c = 0; c < 4; ++c) {
            float m = xls[c] + xrc[c];
            m = fdot2f(e0, wch[c][0], m); m = fdot2f(e1, wch[c][1], m);
            m = fdot2f(e2, wch[c][2], m); m = fdot2f(e3, wch[c][3], m);
            float sv = fmaxf(m, 0.f) + NEG_SLOPE * fminf(m, 0.f);
            p = fmaf(sv, attc[c], p);
        }
        p += __shfl_xor(p, 1); p += __shfl_xor(p, 2); p += __shfl_xor(p, 4); // 8-lane head
        float wgt = __expf(p);
#pragma unroll
        for (int c = 0; c < 4; ++c) num[c] = fmaf(wgt, xls[c], num[c]);
        den += wgt;
        j += 2;
        u0 = u1; u1 = u2; u2 = uT;
        s1 = s2; s2 = sT;
        x0 = xT;
    }
    // combine the two 32-lane chains
#pragma unroll
    for (int c = 0; c < 4; ++c) num[c] += __shfl_xor(num[c], 32);
    den += __shfl_xor(den, 32);
    if (sub == 0) {
        float inv = 1.f / den;
        float base[4];
        if (RES) {
            uint2 ru = *(const uint2*)&out[(size_t)node * 128 + c0];
            h2 r01 = bch2(ru.x), r23 = bch2(ru.y);
            base[0] = (float)r01.x; base[1] = (float)r01.y;
            base[2] = (float)r23.x; base[3] = (float)r23.y;
        } else {
#pragma unroll
            for (int c = 0; c < 4; ++c) base[c] = bias[c0 + c];
        }
        float v[4];
#pragma unroll
        for (int c = 0; c < 4; ++c) v[c] = fmaf(num[c], inv, base[c]);
        if (RELU) {
#pragma unroll
            for (int c = 0; c < 4; ++c) v[c] = fmaxf(v[c], 0.f);
        }
        __half2 o01 = __floats2half2_rn(v[0], v[1]);
        __half2 o23 = __floats2half2_rn(v[2], v[3]);
        uint2 ou; ou.x = *(unsigned*)&o01; ou.y = *(unsigned*)&o23;
        *(uint2*)&out[(size_t)node * 128 + c0] = ou;
    }
}

// ================= CSR aggregation, CT=32 (layers 1, 3) =================
// NOW 2 chains x 16 lanes per node (32 lanes/node): serial edge-iterations
// halve (17 -> ~8.5, matching agg128's validated chain length). Per-lane
// pipeline state unchanged vs the 1-chain version (no VGPR increase).
// Head-reduce offsets (<=8) stay inside each 16-lane chain; one
// shfl_xor(16) combines the chains.
template <int HC, bool RELU, typename OUT>
__global__ __launch_bounds__(256) void agg32_kernel(
    const int* __restrict__ rowptr, const ERec* __restrict__ csr,
    const __half* __restrict__ xl, const __half* __restrict__ xr,
    const float* __restrict__ We,   // [8,32]
    const float* __restrict__ att,  // flat [32]
    const float* __restrict__ bias, // [32]
    OUT* __restrict__ out, int n) {
    int tid = threadIdx.x;
    int node = (blockIdx.x * 256 + tid) >> 5;   // 32 lanes per node
    int lane = tid & 31;
    if (node >= n) return;
    int sub = lane >> 4, q = lane & 15;         // chain id, lane-in-chain
    int c0 = 2 * q;
    h2 wc0[4], wc1[4];
#pragma unroll
    for (int k = 0; k < 4; ++k) {
        wc0[k] = h2{(_Float16)We[(2 * k) * 32 + c0], (_Float16)We[(2 * k + 1) * 32 + c0]};
        wc1[k] = h2{(_Float16)We[(2 * k) * 32 + c0 + 1], (_Float16)We[(2 * k + 1) * 32 + c0 + 1]};
    }
    float att0 = att[c0], att1 = att[c0 + 1];
    int beg = rowptr[node], end = rowptr[node + 1];
    h2 xrh = bch2(*(const unsigned*)&xr[(size_t)node * 32 + c0]);
    float xrc0 = (float)xrh.x, xrc1 = (float)xrh.y;
    float num0 = 0.f, num1 = 0.f, den = 0.f;

    int j = beg + sub;
    uint4 u0, u1, u2; int s0, s1, s2; unsigned x0;
    if (j < end)     { u0 = *(const uint4*)csr[j].ea;     s0 = csr[j].src; }
    if (j + 2 < end) { u1 = *(const uint4*)csr[j + 2].ea; s1 = csr[j + 2].src; }
    if (j + 4 < end) { u2 = *(const uint4*)csr[j + 4].ea; s2 = csr[j + 4].src; }
    if (j < end)     x0 = *(const unsigned*)&xl[(size_t)s0 * 32 + c0];
    while (j < end) {
        uint4 uT; int sT; unsigned xT;
        if (j + 6 < end) { uT = *(const uint4*)csr[j + 6].ea; sT = csr[j + 6].src; }
        if (j + 2 < end) { xT = *(const unsigned*)&xl[(size_t)s1 * 32 + c0]; } // s1: 2 iters old
        h2 e0 = bch2(u0.x), e1 = bch2(u0.y), e2 = bch2(u0.z), e3 = bch2(u0.w);
        h2 xlh = bch2(x0);
        float xls0 = (float)xlh.x, xls1 = (float)xlh.y;
        float m0 = xls0 + xrc0, m1 = xls1 + xrc1;
        m0 = fdot2f(e0, wc0[0], m0); m0 = fdot2f(e1, wc0[1], m0);
        m0 = fdot2f(e2, wc0[2], m0); m0 = fdot2f(e3, wc0[3], m0);
        m1 = fdot2f(e0, wc1[0], m1); m1 = fdot2f(e1, wc1[1], m1);
        m1 = fdot2f(e2, wc1[2], m1); m1 = fdot2f(e3, wc1[3], m1);
        float s0v = fmaxf(m0, 0.f) + NEG_SLOPE * fminf(m0, 0.f);
        float s1v = fmaxf(m1, 0.f) + NEG_SLOPE * fminf(m1, 0.f);
        float p = fmaf(s0v, att0, s1v * att1);
#pragma unroll
        for (int off = HC / 4; off > 0; off >>= 1) p += __shfl_xor(p, off); // head (<=16 lanes)
        float wgt = __expf(p);
        num0 = fmaf(wgt, xls0, num0);
        num1 = fmaf(wgt, xls1, num1);
        den += wgt;
        j += 2;
        u0 = u1; u1 = u2; u2 = uT;
        s1 = s2; s2 = sT;
        x0 = xT;
    }
    // combine the two 16-lane chains
    num0 += __shfl_xor(num0, 16);
    num1 += __shfl_xor(num1, 16);
    den  += __shfl_xor(den, 16);
    if (sub == 0) {
        float inv = 1.f / den;
        float v0 = num0 * inv + bias[c0];
        float v1 = num1 * inv + bias[c0 + 1];
        if (RELU) { v0 = fmaxf(v0, 0.f); v1 = fmaxf(v1, 0.f); }
        if constexpr (sizeof(OUT) == 2) {
            __half2 o = __floats2half2_rn(v0, v1);
            *(__half2*)&out[(size_t)node * 32 + c0] = o;
        } else {
            float2 o; o.x = v0; o.y = v1;
            *(float2*)&out[(size_t)node * 32 + c0] = o;
        }
    }
}

extern "C" void kernel_launch(void* const* d_in, const int* in_sizes, int n_in,
                              void* d_out, int out_size, void* d_ws, size_t ws_size,
                              hipStream_t stream) {
    const float* x    = (const float*)d_in[0];
    const int* ei     = (const int*)d_in[1];
    const float* eatt = (const float*)d_in[2];
    const float* Wl1 = (const float*)d_in[3],  *bl1 = (const float*)d_in[4];
    const float* Wr1 = (const float*)d_in[5],  *br1 = (const float*)d_in[6];
    const float* We1 = (const float*)d_in[7],  *att1 = (const float*)d_in[8];
    const float* b1  = (const float*)d_in[9];
    const float* Wl2 = (const float*)d_in[10], *bl2 = (const float*)d_in[11];
    const float* Wr2 = (const float*)d_in[12], *br2 = (const float*)d_in[13];
    const float* We2 = (const float*)d_in[14], *att2 = (const float*)d_in[15];
    const float* b2  = (const float*)d_in[16], *Rw2 = (const float*)d_in[17];
    const float* Wl3 = (const float*)d_in[18], *bl3 = (const float*)d_in[19];
    const float* Wr3 = (const float*)d_in[20], *br3 = (const float*)d_in[21];
    const float* We3 = (const float*)d_in[22], *att3 = (const float*)d_in[23];
    const float* b3  = (const float*)d_in[24];

    const int* srcp = ei;
    const int* dstp = ei + EE;

    // ---- workspace layout (~70 MB) ----
    char* w = (char*)d_ws;
    size_t off = 0;
    auto alloc = [&](size_t bytes) { char* p = w + off; off += (bytes + 255) & ~size_t(255); return p; };
    int*    rowcnt   = (int*)alloc((size_t)NN * 4);
    int*    rowptr   = (int*)alloc((size_t)(NN + 1) * 4);
    int*    cursor   = (int*)alloc((size_t)NN * 4);
    int*    blocksum = (int*)alloc(256 * 4);
    ERec*   csr      = (ERec*)alloc((size_t)(EE + NN) * sizeof(ERec));
    __half* xlbuf    = (__half*)alloc((size_t)NN * 128 * 2);
    __half* xrbuf    = (__half*)alloc((size_t)NN * 128 * 2);
    __half* hA       = (__half*)alloc((size_t)NN * 32 * 2);
    __half* hB       = (__half*)alloc((size_t)NN * 128 * 2);

    int nb = cdiv(NN, 256);

    // ---- CSR build (self-loop in front slot of each row) ----
    hipMemsetAsync(rowcnt, 0, (size_t)NN * 4, stream);
    hist_kernel<<<cdiv(EE / 4, 256), 256, 0, stream>>>((const int4*)dstp, rowcnt, EE / 4);
    scana_kernel<<<nb, 256, 0, stream>>>(rowcnt, blocksum, NN);
    scanb_kernel<<<nb, 256, 0, stream>>>(rowcnt, blocksum, nb, rowptr, cursor, csr, NN);
    scatter_kernel<<<cdiv(EE, 256), 256, 0, stream>>>(
        srcp, dstp, eatt, cursor, csr, EE);

    // ---- fused: loop_sea + node_linear layer 1 ----
    constexpr int NB1 = (NN + 7) / 8;
    int nb_ls = cdiv(NN, 4);
    fused_nl1_loopsea_kernel<NB1><<<NB1 + nb_ls, 256, 0, stream>>>(
        x, Wl1, bl1, Wr1, br1, xlbuf, xrbuf, rowptr, csr, NN);

    // ---- layer 1 aggregation: H=4, C=8 (CT=32, 2 chains/node) ----
    agg32_kernel<8, true, __half><<<cdiv(NN, 8), 256, 0, stream>>>(
        rowptr, csr, xlbuf, xrbuf, We1, att1, b1, hA, NN);

    // ---- layer 2: IN=32 -> H=4, C=32 (CT=128), residual fused into nlh2 ----
    nlh2_res_kernel<32><<<cdiv(NN, 32), 256, 0, stream>>>(
        hA, Wl2, bl2, Wr2, br2, Rw2, b2, xlbuf, xrbuf, hB, NN);
    agg128_kernel<true, true><<<cdiv(NN, 4), 256, 0, stream>>>(
        rowptr, csr, xlbuf, xrbuf, We2, att2, b2, hB, NN);

    // ---- layer 3: IN=128 -> H=1, C=32 (CT=32, 2 chains/node) ----
    node_linear_h_kernel<128, 32, 64><<<cdiv(NN, 64), 256, 0, stream>>>(
        hB, Wl3, bl3, Wr3, br3, xlbuf, xrbuf, NN);
    agg32_kernel<32, false, float><<<cdiv(NN, 8), 256, 0, stream>>>(
        rowptr, csr, xlbuf, xrbuf, We3, att3, b3,
        (float*)d_out, NN);
}